// Round 4
// baseline (242.111 us; speedup 1.0000x reference)
//
#include <hip/hip_runtime.h>
#include <hip/hip_bf16.h>

#define BSAMP 8192
#define NCLS 400
#define DIM 768
#define LOGITS_SIZE (16384LL * 400LL)
#define W_ELEMS (NCLS * DIM)

// grid: 256 groups x 21 blocks = 5376. slot<5 -> GEMM (1280: m-major, 64 rows x 80 cols),
// slot>=5 -> mask (4096 blocks x 4 pairs)
#define TOTAL_BLOCKS 5376

typedef __attribute__((ext_vector_type(8))) short short8;
typedef __attribute__((ext_vector_type(4))) float floatx4;

// fp32 -> bf16 round-half-up, two at a time: 2 adds + 1 v_perm
__device__ inline unsigned int packbf(float a, float b) {
    unsigned int ua = __float_as_uint(a) + 0x8000u;
    unsigned int ub = __float_as_uint(b) + 0x8000u;
    return __builtin_amdgcn_perm(ub, ua, 0x07060302u);  // [ua.b2,ua.b3,ub.b2,ub.b3]
}

__device__ inline short8 cvt8(float4 lo, float4 hi) {
    union { unsigned int u[4]; short8 s; } r;
    r.u[0] = packbf(lo.x, lo.y);
    r.u[1] = packbf(lo.z, lo.w);
    r.u[2] = packbf(hi.x, hi.y);
    r.u[3] = packbf(hi.z, hi.w);
    return r.s;
}

// W fp32 -> bf16 pre-convert (0.6 MB into d_ws)
__global__ void cvtW_kernel(const float* __restrict__ W, unsigned short* __restrict__ ws) {
    int i = (blockIdx.x * 256 + threadIdx.x) * 4;
    if (i < W_ELEMS) {
        float4 f = *(const float4*)(W + i);
        uint2 r;
        r.x = packbf(f.x, f.y);
        r.y = packbf(f.z, f.w);
        *(uint2*)(ws + i) = r;
    }
}

__device__ inline float bilin14(const float* m14, float Y, float X, float eH, float eW) {
    float sy = fmaxf((Y + 0.5f) * 14.0f / eH - 0.5f, 0.0f);
    float sx = fmaxf((X + 0.5f) * 14.0f / eW - 0.5f, 0.0f);
    float r0f = floorf(sy);
    float c0f = floorf(sx);
    int r0 = (int)r0f;
    int r1 = min(r0 + 1, 13);
    int c0 = (int)c0f;
    int c1 = min(c0 + 1, 13);
    float fy = sy - r0f;
    float fx = sx - c0f;
    float g00 = m14[r0 * 14 + c0];
    float g01 = m14[r0 * 14 + c1];
    float g10 = m14[r1 * 14 + c0];
    float g11 = m14[r1 * 14 + c1];
    return g00 * (1.f - fy) * (1.f - fx) + g01 * (1.f - fy) * fx +
           g10 * fy * (1.f - fx) + g11 * fy * fx;
}

template <bool USE_WS>
__global__ __launch_bounds__(256, 4) void fused_kernel(const float* __restrict__ attn,
                                                       const int* __restrict__ pos,
                                                       const float* __restrict__ E,
                                                       const float* __restrict__ W,
                                                       const float* __restrict__ bias,
                                                       const unsigned short* __restrict__ wsW,
                                                       float* __restrict__ out) {
    __shared__ float m14s[4][208];
    __shared__ float a7s[4][56];
    __shared__ float mvs[4][56];

    const int grp  = blockIdx.x / 21;
    const int slot = blockIdx.x - grp * 21;
    const int t    = threadIdx.x;
    const int wv   = t >> 6, ln = t & 63;

    if (slot < 5) {
        // ================= GEMM: 64(M) x 80(N), K=768, no LDS, no barriers =================
        // wave = one 16-row m-frag x five 16-col n-frags; depth-1 register prefetch
        const int m0 = grp * 64;
        const int n0 = slot * 80;
        const int quad = ln >> 4, l16 = ln & 15;

        const float* aBase = E + (size_t)(m0 + wv * 16 + l16) * DIM + quad * 8;
        const size_t bBase = (size_t)(n0 + l16) * DIM + quad * 8;   // + ni*16*DIM + k

        floatx4 acc[5];
#pragma unroll
        for (int ni = 0; ni < 5; ++ni) acc[ni] = (floatx4){0.f, 0.f, 0.f, 0.f};

        float4 a0c, a1c, b0c[5], b1c[5];
        short8 bc[5];
        a0c = *(const float4*)(aBase);
        a1c = *(const float4*)(aBase + 4);
#pragma unroll
        for (int ni = 0; ni < 5; ++ni) {
            if (USE_WS) bc[ni] = *(const short8*)(wsW + bBase + (size_t)ni * 16 * DIM);
            else {
                b0c[ni] = *(const float4*)(W + bBase + (size_t)ni * 16 * DIM);
                b1c[ni] = *(const float4*)(W + bBase + (size_t)ni * 16 * DIM + 4);
            }
        }

        for (int it = 0; it < 24; ++it) {
            float4 a0n, a1n, b0n[5], b1n[5];
            short8 bn[5];
            if (it < 23) {
                const int kn = (it + 1) * 32;
                a0n = *(const float4*)(aBase + kn);
                a1n = *(const float4*)(aBase + kn + 4);
#pragma unroll
                for (int ni = 0; ni < 5; ++ni) {
                    if (USE_WS) bn[ni] = *(const short8*)(wsW + bBase + (size_t)ni * 16 * DIM + kn);
                    else {
                        b0n[ni] = *(const float4*)(W + bBase + (size_t)ni * 16 * DIM + kn);
                        b1n[ni] = *(const float4*)(W + bBase + (size_t)ni * 16 * DIM + kn + 4);
                    }
                }
            }
            short8 af = cvt8(a0c, a1c);
#pragma unroll
            for (int ni = 0; ni < 5; ++ni) {
                short8 bfr = USE_WS ? bc[ni] : cvt8(b0c[ni], b1c[ni]);
                acc[ni] = __builtin_amdgcn_mfma_f32_16x16x32_bf16(af, bfr, acc[ni], 0, 0, 0);
            }
            if (it < 23) {
                a0c = a0n; a1c = a1n;
#pragma unroll
                for (int ni = 0; ni < 5; ++ni) {
                    if (USE_WS) bc[ni] = bn[ni];
                    else { b0c[ni] = b0n[ni]; b1c[ni] = b1n[ni]; }
                }
            }
        }

        // epilogue: C/D layout col=lane&15, row=quad*4+reg
        const int rowBase = m0 + wv * 16 + quad * 4;
#pragma unroll
        for (int ni = 0; ni < 5; ++ni) {
            int col = n0 + ni * 16 + l16;
            float bv = bias[col];
#pragma unroll
            for (int r = 0; r < 4; ++r) {
                out[(size_t)(rowBase + r) * NCLS + col] = acc[ni][r] + bv;
            }
        }
    } else {
        // ================= mask path: 4 (sample,box) pairs per block, 1 per wave =================
        const int p = (grp * 16 + (slot - 5)) * 4 + wv;   // 0..16383 output row
        const int b = p & (BSAMP - 1);
        const int o = p >> 13;
        float* m14 = m14s[wv];

        for (int i = ln; i < 196; i += 64) m14[i] = attn[(size_t)b * 196 + i];

        const int* pb = pos + (size_t)b * 12;
        const float topf  = (float)(pb[o * 4 + 0] - pb[8]);
        const float leftf = (float)(pb[o * 4 + 1] - pb[9]);
        const float oH = (float)pb[o * 4 + 2];
        const float oW = (float)pb[o * 4 + 3];
        const float eH = (float)pb[10];
        const float eW = (float)pb[11];
        __syncthreads();

        const int i7 = ln / 7, j7 = ln - i7 * 7;
        if (ln < 49) {
            float s = 0.f;
#pragma unroll
            for (int dy = 0; dy < 2; ++dy) {
                int oy = 2 * i7 + dy;
                float ty = fmaxf((oy + 0.5f) * oH / 14.0f - 0.5f, 0.0f);
                float y0 = floorf(ty);
                float y1 = fminf(y0 + 1.0f, oH - 1.0f);
                float wy = ty - y0;
                float Y0 = topf + y0, Y1 = topf + y1;
#pragma unroll
                for (int dx = 0; dx < 2; ++dx) {
                    int ox = 2 * j7 + dx;
                    float tx = fmaxf((ox + 0.5f) * oW / 14.0f - 0.5f, 0.0f);
                    float x0 = floorf(tx);
                    float x1 = fminf(x0 + 1.0f, oW - 1.0f);
                    float wx = tx - x0;
                    float X0 = leftf + x0, X1 = leftf + x1;
                    float v00 = bilin14(m14, Y0, X0, eH, eW);
                    float v01 = bilin14(m14, Y0, X1, eH, eW);
                    float v10 = bilin14(m14, Y1, X0, eH, eW);
                    float v11 = bilin14(m14, Y1, X1, eH, eW);
                    float cm = v00 * (1.f - wy) * (1.f - wx) + v01 * (1.f - wy) * wx +
                               v10 * wy * (1.f - wx) + v11 * wy * wx;
                    s += cm;
                }
            }
            a7s[wv][ln] = s * 0.25f;
        }
        __syncthreads();

        if (ln < 49) {  // stable top-25 rank (jax.lax.top_k tie-break to lower index)
            float mine = a7s[wv][ln];
            int cnt = 0;
#pragma unroll 7
            for (int s2 = 0; s2 < 49; ++s2) {
                float v = a7s[wv][s2];
                cnt += (v > mine) || (v == mine && s2 < ln);
            }
            mvs[wv][ln] = (cnt < 25) ? 0.0f : 1.0f;
        }
        __syncthreads();

        float* ob = out + LOGITS_SIZE + (size_t)p * 196;
        for (int i = ln; i < 196; i += 64) {
            int oy = i / 14, ox = i - oy * 14;
            ob[i] = mvs[wv][(oy >> 1) * 7 + (ox >> 1)];
        }
    }
}

extern "C" void kernel_launch(void* const* d_in, const int* in_sizes, int n_in,
                              void* d_out, int out_size, void* d_ws, size_t ws_size,
                              hipStream_t stream) {
    const float* attn = (const float*)d_in[0];
    const int*   pos  = (const int*)d_in[1];
    const float* E    = (const float*)d_in[2];
    const float* W    = (const float*)d_in[3];
    const float* bias = (const float*)d_in[4];
    float* out = (float*)d_out;

    if (ws_size >= (size_t)W_ELEMS * 2) {
        unsigned short* ws = (unsigned short*)d_ws;
        cvtW_kernel<<<300, 256, 0, stream>>>(W, ws);
        fused_kernel<true><<<TOTAL_BLOCKS, 256, 0, stream>>>(attn, pos, E, W, bias, ws, out);
    } else {
        fused_kernel<false><<<TOTAL_BLOCKS, 256, 0, stream>>>(attn, pos, E, W, bias, nullptr, out);
    }
}

// Round 5
// 150.995 us; speedup vs baseline: 1.6034x; 1.6034x over previous
//
#include <hip/hip_runtime.h>
#include <hip/hip_bf16.h>

#define BSAMP 8192
#define NCLS 400
#define DIM 768
#define LOGITS_SIZE (16384LL * 400LL)
#define GEMM_BLOCKS 640     // 128 m-tiles(128 rows) x 5 n-tiles(80 cols); n fastest (A L3 reuse)
#define MASK_BLOCKS 4096    // 4 (sample,box) pairs per block, 1 per wave

typedef __attribute__((ext_vector_type(8))) short short8;
typedef __attribute__((ext_vector_type(4))) float floatx4;

// fp32 -> bf16 round-half-up, two at a time: 2 adds + 1 v_perm
__device__ inline unsigned int packbf(float a, float b) {
    unsigned int ua = __float_as_uint(a) + 0x8000u;
    unsigned int ub = __float_as_uint(b) + 0x8000u;
    return __builtin_amdgcn_perm(ub, ua, 0x07060302u);  // [ua.b2,ua.b3,ub.b2,ub.b3]
}

__device__ inline short8 cvt8(float4 lo, float4 hi) {
    union { unsigned int u[4]; short8 s; } r;
    r.u[0] = packbf(lo.x, lo.y);
    r.u[1] = packbf(lo.z, lo.w);
    r.u[2] = packbf(hi.x, hi.y);
    r.u[3] = packbf(hi.z, hi.w);
    return r.s;
}

__device__ inline float bilin14(const float* m14, float Y, float X, float eH, float eW) {
    float sy = fmaxf((Y + 0.5f) * 14.0f / eH - 0.5f, 0.0f);
    float sx = fmaxf((X + 0.5f) * 14.0f / eW - 0.5f, 0.0f);
    float r0f = floorf(sy);
    float c0f = floorf(sx);
    int r0 = (int)r0f;
    int r1 = min(r0 + 1, 13);
    int c0 = (int)c0f;
    int c1 = min(c0 + 1, 13);
    float fy = sy - r0f;
    float fx = sx - c0f;
    float g00 = m14[r0 * 14 + c0];
    float g01 = m14[r0 * 14 + c1];
    float g10 = m14[r1 * 14 + c0];
    float g11 = m14[r1 * 14 + c1];
    return g00 * (1.f - fy) * (1.f - fx) + g01 * (1.f - fy) * fx +
           g10 * fy * (1.f - fx) + g11 * fy * fx;
}

// launch_bounds(256,3): cap 170 VGPR so the one-stage-early prefetch regs stay live
// (R2/R4 lesson: tighter caps make the compiler sink loads and serialize).
__global__ __launch_bounds__(256, 3) void fused_kernel(const float* __restrict__ attn,
                                                       const int* __restrict__ pos,
                                                       const float* __restrict__ E,
                                                       const float* __restrict__ W,
                                                       const float* __restrict__ bias,
                                                       float* __restrict__ out) {
    __shared__ __align__(16) union {
        struct { unsigned short A[2][128 * 40]; unsigned short B[2][80 * 40]; } g;  // 33280 B
        struct { float m14[4][208]; float a7[4][56]; float mv[4][56]; } m;          //  5120 B
    } sm;

    const int bx = blockIdx.x;
    const int t  = threadIdx.x;
    const int wv = t >> 6, ln = t & 63;

    if (bx < GEMM_BLOCKS) {
        // ============ GEMM: 128(M) x 80(N), BK=32, double-buffered LDS ============
        const int n0 = (bx % 5) * 80;            // n fastest: 5 sharers of an A-slice adjacent
        const int m0 = (bx / 5) * 128;
        const int quad = ln >> 4, l16 = ln & 15;

        // staging: thread t -> row t/2 (A: 0..127; B: 0..79 for t<160), 16 k-floats at (t&1)*16
        const int sRow = t >> 1;
        const int sCol = (t & 1) << 4;
        const float* aSrc = E + (size_t)(m0 + sRow) * DIM + sCol;
        const float* bSrc = W + (size_t)(n0 + sRow) * DIM + sCol;  // t<160 only

        floatx4 acc[2][5];
#pragma unroll
        for (int mi = 0; mi < 2; ++mi)
#pragma unroll
            for (int ni = 0; ni < 5; ++ni)
                acc[mi][ni] = (floatx4){0.f, 0.f, 0.f, 0.f};

        // prologue: load slab 0 into regs
        float4 pa0 = *(const float4*)(aSrc);
        float4 pa1 = *(const float4*)(aSrc + 4);
        float4 pa2 = *(const float4*)(aSrc + 8);
        float4 pa3 = *(const float4*)(aSrc + 12);
        float4 pb0, pb1, pb2, pb3;
        if (t < 160) {
            pb0 = *(const float4*)(bSrc);
            pb1 = *(const float4*)(bSrc + 4);
            pb2 = *(const float4*)(bSrc + 8);
            pb3 = *(const float4*)(bSrc + 12);
        }

#pragma unroll 2
        for (int it = 0; it < 24; ++it) {
            const int cur = it & 1;
            // store slab `it` (regs -> LDS, cvt inline)
            {
                unsigned short* wa = &sm.g.A[cur][sRow * 40 + sCol];
                *(short8*)(wa)     = cvt8(pa0, pa1);
                *(short8*)(wa + 8) = cvt8(pa2, pa3);
                if (t < 160) {
                    unsigned short* wb = &sm.g.B[cur][sRow * 40 + sCol];
                    *(short8*)(wb)     = cvt8(pb0, pb1);
                    *(short8*)(wb + 8) = cvt8(pb2, pb3);
                }
            }
            // issue loads for slab it+1 now; consumed at next iter's store (one stage of cover)
            if (it < 23) {
                const int kn = (it + 1) * 32;
                pa0 = *(const float4*)(aSrc + kn);
                pa1 = *(const float4*)(aSrc + kn + 4);
                pa2 = *(const float4*)(aSrc + kn + 8);
                pa3 = *(const float4*)(aSrc + kn + 12);
                if (t < 160) {
                    pb0 = *(const float4*)(bSrc + kn);
                    pb1 = *(const float4*)(bSrc + kn + 4);
                    pb2 = *(const float4*)(bSrc + kn + 8);
                    pb3 = *(const float4*)(bSrc + kn + 12);
                }
            }
            __syncthreads();  // buf[cur] ready (also protects buf[cur] from it+2's store)

            short8 af0 = *(const short8*)&sm.g.A[cur][(wv * 32 + l16) * 40 + quad * 8];
            short8 af1 = *(const short8*)&sm.g.A[cur][(wv * 32 + 16 + l16) * 40 + quad * 8];
#pragma unroll
            for (int ni = 0; ni < 5; ++ni) {
                short8 bfr = *(const short8*)&sm.g.B[cur][(ni * 16 + l16) * 40 + quad * 8];
                acc[0][ni] = __builtin_amdgcn_mfma_f32_16x16x32_bf16(af0, bfr, acc[0][ni], 0, 0, 0);
                acc[1][ni] = __builtin_amdgcn_mfma_f32_16x16x32_bf16(af1, bfr, acc[1][ni], 0, 0, 0);
            }
        }

        // epilogue: C/D layout col=lane&15, row=quad*4+reg (HW-verified)
#pragma unroll
        for (int ni = 0; ni < 5; ++ni) {
            int col = n0 + ni * 16 + l16;
            float bv = bias[col];
#pragma unroll
            for (int mi = 0; mi < 2; ++mi) {
                int rowBase = m0 + wv * 32 + mi * 16 + quad * 4;
#pragma unroll
                for (int r = 0; r < 4; ++r) {
                    out[(size_t)(rowBase + r) * NCLS + col] = acc[mi][ni][r] + bv;
                }
            }
        }
    } else {
        // ============ mask path: 4 (sample,box) pairs per block, 1 per wave ============
        const int p = (bx - GEMM_BLOCKS) * 4 + wv;   // 0..16383 output row
        const int b = p & (BSAMP - 1);
        const int o = p >> 13;
        float* m14 = sm.m.m14[wv];

        for (int i = ln; i < 196; i += 64) m14[i] = attn[(size_t)b * 196 + i];

        const int* pb = pos + (size_t)b * 12;
        const float topf  = (float)(pb[o * 4 + 0] - pb[8]);
        const float leftf = (float)(pb[o * 4 + 1] - pb[9]);
        const float oH = (float)pb[o * 4 + 2];
        const float oW = (float)pb[o * 4 + 3];
        const float eH = (float)pb[10];
        const float eW = (float)pb[11];
        __syncthreads();

        const int i7 = ln / 7, j7 = ln - i7 * 7;
        if (ln < 49) {
            float s = 0.f;
#pragma unroll
            for (int dy = 0; dy < 2; ++dy) {
                int oy = 2 * i7 + dy;
                float ty = fmaxf((oy + 0.5f) * oH / 14.0f - 0.5f, 0.0f);
                float y0 = floorf(ty);
                float y1 = fminf(y0 + 1.0f, oH - 1.0f);
                float wy = ty - y0;
                float Y0 = topf + y0, Y1 = topf + y1;
#pragma unroll
                for (int dx = 0; dx < 2; ++dx) {
                    int ox = 2 * j7 + dx;
                    float tx = fmaxf((ox + 0.5f) * oW / 14.0f - 0.5f, 0.0f);
                    float x0 = floorf(tx);
                    float x1 = fminf(x0 + 1.0f, oW - 1.0f);
                    float wx = tx - x0;
                    float X0 = leftf + x0, X1 = leftf + x1;
                    float v00 = bilin14(m14, Y0, X0, eH, eW);
                    float v01 = bilin14(m14, Y0, X1, eH, eW);
                    float v10 = bilin14(m14, Y1, X0, eH, eW);
                    float v11 = bilin14(m14, Y1, X1, eH, eW);
                    float cm = v00 * (1.f - wy) * (1.f - wx) + v01 * (1.f - wy) * wx +
                               v10 * wy * (1.f - wx) + v11 * wy * wx;
                    s += cm;
                }
            }
            sm.m.a7[wv][ln] = s * 0.25f;
        }
        __syncthreads();

        if (ln < 49) {  // stable top-25 rank (jax.lax.top_k tie-break to lower index)
            float mine = sm.m.a7[wv][ln];
            int cnt = 0;
#pragma unroll 7
            for (int s2 = 0; s2 < 49; ++s2) {
                float v = sm.m.a7[wv][s2];
                cnt += (v > mine) || (v == mine && s2 < ln);
            }
            sm.m.mv[wv][ln] = (cnt < 25) ? 0.0f : 1.0f;
        }
        __syncthreads();

        float* ob = out + LOGITS_SIZE + (size_t)p * 196;
        for (int i = ln; i < 196; i += 64) {
            int oy = i / 14, ox = i - oy * 14;
            ob[i] = sm.m.mv[wv][(oy >> 1) * 7 + (ox >> 1)];
        }
    }
}

extern "C" void kernel_launch(void* const* d_in, const int* in_sizes, int n_in,
                              void* d_out, int out_size, void* d_ws, size_t ws_size,
                              hipStream_t stream) {
    const float* attn = (const float*)d_in[0];
    const int*   pos  = (const int*)d_in[1];
    const float* E    = (const float*)d_in[2];
    const float* W    = (const float*)d_in[3];
    const float* bias = (const float*)d_in[4];
    float* out = (float*)d_out;

    fused_kernel<<<GEMM_BLOCKS + MASK_BLOCKS, 256, 0, stream>>>(attn, pos, E, W, bias, out);
}

// Round 6
// 150.680 us; speedup vs baseline: 1.6068x; 1.0021x over previous
//
#include <hip/hip_runtime.h>
#include <hip/hip_bf16.h>
#include <stdint.h>
#include <type_traits>

#define BSAMP 8192
#define NCLS 400
#define DIM 768
#define LOGITS_SIZE (16384LL * 400LL)
#define GEMM_BLOCKS 640     // 128 m-bands(128 rows) x 5 n(80 cols), XCD-swizzled
#define MASK_BLOCKS 4096    // 4 (sample,box) pairs per block, 1 per wave
#define W_ELEMS (NCLS * DIM)

typedef __attribute__((ext_vector_type(8))) short short8;
typedef __attribute__((ext_vector_type(4))) float floatx4;

// fp32 -> bf16 round-half-up, two at a time: 2 adds + 1 v_perm
__device__ inline unsigned int packbf(float a, float b) {
    unsigned int ua = __float_as_uint(a) + 0x8000u;
    unsigned int ub = __float_as_uint(b) + 0x8000u;
    return __builtin_amdgcn_perm(ub, ua, 0x07060302u);  // [ua.b2,ua.b3,ub.b2,ub.b3]
}

__device__ inline short8 cvt8(float4 lo, float4 hi) {
    union { unsigned int u[4]; short8 s; } r;
    r.u[0] = packbf(lo.x, lo.y);
    r.u[1] = packbf(lo.z, lo.w);
    r.u[2] = packbf(hi.x, hi.y);
    r.u[3] = packbf(hi.z, hi.w);
    return r.s;
}

// async global->LDS DMA, 16 B per lane; dest = wave-uniform base + lane*16.
// Cannot be sunk across s_barrier by the compiler (LDS side effect) -> real pipelining.
__device__ inline void gload16(const void* g, void* l) {
    __builtin_amdgcn_global_load_lds((const __attribute__((address_space(1))) void*)g,
                                     (__attribute__((address_space(3))) void*)l, 16, 0, 0);
}

// W fp32 -> bf16 pre-convert (0.6 MB into d_ws); re-run every launch (ws re-poisoned)
__global__ void cvtW_kernel(const float* __restrict__ W, unsigned short* __restrict__ ws) {
    int i = (blockIdx.x * 256 + threadIdx.x) * 4;
    if (i < W_ELEMS) {
        float4 f = *(const float4*)(W + i);
        uint2 r;
        r.x = packbf(f.x, f.y);
        r.y = packbf(f.z, f.w);
        *(uint2*)(ws + i) = r;
    }
}

__device__ inline float bilin14(const float* m14, float Y, float X, float eH, float eW) {
    float sy = fmaxf((Y + 0.5f) * 14.0f / eH - 0.5f, 0.0f);
    float sx = fmaxf((X + 0.5f) * 14.0f / eW - 0.5f, 0.0f);
    float r0f = floorf(sy);
    float c0f = floorf(sx);
    int r0 = (int)r0f;
    int r1 = min(r0 + 1, 13);
    int c0 = (int)c0f;
    int c1 = min(c0 + 1, 13);
    float fy = sy - r0f;
    float fx = sx - c0f;
    float g00 = m14[r0 * 14 + c0];
    float g01 = m14[r0 * 14 + c1];
    float g10 = m14[r1 * 14 + c0];
    float g11 = m14[r1 * 14 + c1];
    return g00 * (1.f - fy) * (1.f - fx) + g01 * (1.f - fy) * fx +
           g10 * fy * (1.f - fx) + g11 * fy * fx;
}

struct MaskSm { float m14[4][208]; float a7[4][56]; float mv[4][56]; };  // 5120 B

template <bool USE_WS>
struct GemmSm {
    float A[2][128 * 32];                                                 // 32 KB fp32, swizzled
    typename std::conditional<USE_WS, unsigned short, float>::type B[2][80 * 32];
};

template <bool USE_WS>
__global__ __launch_bounds__(256, 2) void fused_kernel(const float* __restrict__ attn,
                                                       const int* __restrict__ pos,
                                                       const float* __restrict__ E,
                                                       const float* __restrict__ W,
                                                       const float* __restrict__ bias,
                                                       const unsigned short* __restrict__ wsW,
                                                       float* __restrict__ out) {
    __shared__ __align__(16) union SmU {
        GemmSm<USE_WS> g;   // 43008 B (ws) / 53248 B (fallback)
        MaskSm m;           //  5120 B
    } sm;

    const int bx = blockIdx.x;
    const int t  = threadIdx.x;
    const int wv = t >> 6, ln = t & 63;

    if (bx < GEMM_BLOCKS) {
        // ---- XCD swizzle: bx%8 -> XCD (m09); put all 5 n-blocks of one m-band on one XCD ----
        const int xcd = bx & 7, li = bx >> 3;       // li 0..79 within XCD
        const int band = (li / 5) * 8 + xcd;        // 0..127
        const int n0 = (li % 5) * 80;
        const int m0 = band << 7;                   // *128
        const int quad = ln >> 4, l16 = ln & 15;

        // ---- async stagers (source-side XOR swizzle for conflict-free LDS reads) ----
        // A: [row][32 fp32], phys chunk c (4 fp32) of row r holds logical chunk c^(r&7)
        auto stageA = [&](int k0, float* buf) {
#pragma unroll
            for (int j = 0; j < 4; ++j) {
                int r = wv * 32 + j * 8 + (ln >> 3);
                int c = ln & 7;
                const float* src = E + (size_t)(m0 + r) * DIM + k0 + 4 * (c ^ (r & 7));
                gload16(src, buf + (wv * 32 + j * 8) * 32);
            }
        };
        // B bf16: [n][32 bf16], phys chunk c (8 bf16) of row n holds logical chunk c^((n>>1)&3)
        auto stageBw = [&](int k0, unsigned short* buf) {
            for (int j = wv; j < 5; j += 4) {
                int row = j * 16 + (ln >> 2);
                int c = ln & 3;
                const unsigned short* src = wsW + (size_t)(n0 + row) * DIM + k0 + 8 * (c ^ ((row >> 1) & 3));
                gload16(src, buf + (j * 16) * 32);
            }
        };
        // B fp32 fallback: same scheme as A
        auto stageBf = [&](int k0, float* buf) {
            for (int j = wv; j < 10; j += 4) {
                int r = j * 8 + (ln >> 3);
                int c = ln & 7;
                const float* src = W + (size_t)(n0 + r) * DIM + k0 + 4 * (c ^ (r & 7));
                gload16(src, buf + (j * 8) * 32);
            }
        };
        auto stage = [&](int k0, int buf) {
            stageA(k0, sm.g.A[buf]);
            if constexpr (USE_WS) stageBw(k0, sm.g.B[buf]);
            else stageBf(k0, (float*)sm.g.B[buf]);
        };

        floatx4 acc[2][5];
#pragma unroll
        for (int mi = 0; mi < 2; ++mi)
#pragma unroll
            for (int ni = 0; ni < 5; ++ni)
                acc[mi][ni] = (floatx4){0.f, 0.f, 0.f, 0.f};

        // ---- 2-deep pipeline: issue 2 slabs, then compute / barrier / refill ----
        stage(0, 0);
        stage(32, 1);
        __syncthreads();   // drains prologue loads once

        for (int it = 0; it < 24; ++it) {
            const int cur = it & 1;
            const float* aS = sm.g.A[cur];

            short8 af[2];
#pragma unroll
            for (int mi = 0; mi < 2; ++mi) {
                int r = wv * 32 + mi * 16 + l16;
                int rx = r & 7;
                const float* rp = aS + r * 32;
                float4 lo = *(const float4*)(rp + (((quad << 1) ^ rx) << 2));
                float4 hi = *(const float4*)(rp + ((((quad << 1) | 1) ^ rx) << 2));
                af[mi] = cvt8(lo, hi);
            }
#pragma unroll
            for (int ni = 0; ni < 5; ++ni) {
                int row = ni * 16 + l16;
                short8 bfr;
                if constexpr (USE_WS) {
                    bfr = *(const short8*)(sm.g.B[cur] + row * 32 + 8 * (quad ^ ((row >> 1) & 3)));
                } else {
                    int rx = row & 7;
                    const float* rp = (const float*)sm.g.B[cur] + row * 32;
                    float4 lo = *(const float4*)(rp + (((quad << 1) ^ rx) << 2));
                    float4 hi = *(const float4*)(rp + ((((quad << 1) | 1) ^ rx) << 2));
                    bfr = cvt8(lo, hi);
                }
                acc[0][ni] = __builtin_amdgcn_mfma_f32_16x16x32_bf16(af[0], bfr, acc[0][ni], 0, 0, 0);
                acc[1][ni] = __builtin_amdgcn_mfma_f32_16x16x32_bf16(af[1], bfr, acc[1][ni], 0, 0, 0);
            }

            __syncthreads();          // readers of buf[cur] done; drains stage(it+1) after a full compute-phase in flight
            if (it < 22) stage((it + 2) * 32, cur);   // barrier-pinned: cannot be sunk
        }

        // ---- epilogue: C/D layout col=lane&15, row=quad*4+reg (HW-verified) ----
#pragma unroll
        for (int ni = 0; ni < 5; ++ni) {
            int col = n0 + ni * 16 + l16;
            float bv = bias[col];
#pragma unroll
            for (int mi = 0; mi < 2; ++mi) {
                int rowBase = m0 + wv * 32 + mi * 16 + quad * 4;
#pragma unroll
                for (int r = 0; r < 4; ++r) {
                    out[(size_t)(rowBase + r) * NCLS + col] = acc[mi][ni][r] + bv;
                }
            }
        }
    } else {
        // ============ mask path: 4 (sample,box) pairs per block, 1 per wave ============
        const int p = (bx - GEMM_BLOCKS) * 4 + wv;   // 0..16383 output row
        const int b = p & (BSAMP - 1);
        const int o = p >> 13;
        float* m14 = sm.m.m14[wv];

        for (int i = ln; i < 196; i += 64) m14[i] = attn[(size_t)b * 196 + i];

        const int* pb = pos + (size_t)b * 12;
        const float topf  = (float)(pb[o * 4 + 0] - pb[8]);
        const float leftf = (float)(pb[o * 4 + 1] - pb[9]);
        const float oH = (float)pb[o * 4 + 2];
        const float oW = (float)pb[o * 4 + 3];
        const float eH = (float)pb[10];
        const float eW = (float)pb[11];
        __syncthreads();

        const int i7 = ln / 7, j7 = ln - i7 * 7;
        if (ln < 49) {
            float s = 0.f;
#pragma unroll
            for (int dy = 0; dy < 2; ++dy) {
                int oy = 2 * i7 + dy;
                float ty = fmaxf((oy + 0.5f) * oH / 14.0f - 0.5f, 0.0f);
                float y0 = floorf(ty);
                float y1 = fminf(y0 + 1.0f, oH - 1.0f);
                float wy = ty - y0;
                float Y0 = topf + y0, Y1 = topf + y1;
#pragma unroll
                for (int dx = 0; dx < 2; ++dx) {
                    int ox = 2 * j7 + dx;
                    float tx = fmaxf((ox + 0.5f) * oW / 14.0f - 0.5f, 0.0f);
                    float x0 = floorf(tx);
                    float x1 = fminf(x0 + 1.0f, oW - 1.0f);
                    float wx = tx - x0;
                    float X0 = leftf + x0, X1 = leftf + x1;
                    float v00 = bilin14(m14, Y0, X0, eH, eW);
                    float v01 = bilin14(m14, Y0, X1, eH, eW);
                    float v10 = bilin14(m14, Y1, X0, eH, eW);
                    float v11 = bilin14(m14, Y1, X1, eH, eW);
                    float cm = v00 * (1.f - wy) * (1.f - wx) + v01 * (1.f - wy) * wx +
                               v10 * wy * (1.f - wx) + v11 * wy * wx;
                    s += cm;
                }
            }
            sm.m.a7[wv][ln] = s * 0.25f;
        }
        __syncthreads();

        if (ln < 49) {  // stable top-25 rank (jax.lax.top_k tie-break to lower index)
            float mine = sm.m.a7[wv][ln];
            int cnt = 0;
#pragma unroll 7
            for (int s2 = 0; s2 < 49; ++s2) {
                float v = sm.m.a7[wv][s2];
                cnt += (v > mine) || (v == mine && s2 < ln);
            }
            sm.m.mv[wv][ln] = (cnt < 25) ? 0.0f : 1.0f;
        }
        __syncthreads();

        float* ob = out + LOGITS_SIZE + (size_t)p * 196;
        for (int i = ln; i < 196; i += 64) {
            int oy = i / 14, ox = i - oy * 14;
            ob[i] = sm.m.mv[wv][(oy >> 1) * 7 + (ox >> 1)];
        }
    }
}

extern "C" void kernel_launch(void* const* d_in, const int* in_sizes, int n_in,
                              void* d_out, int out_size, void* d_ws, size_t ws_size,
                              hipStream_t stream) {
    const float* attn = (const float*)d_in[0];
    const int*   pos  = (const int*)d_in[1];
    const float* E    = (const float*)d_in[2];
    const float* W    = (const float*)d_in[3];
    const float* bias = (const float*)d_in[4];
    float* out = (float*)d_out;

    if (ws_size >= (size_t)W_ELEMS * 2) {
        unsigned short* ws = (unsigned short*)d_ws;
        cvtW_kernel<<<300, 256, 0, stream>>>(W, ws);
        fused_kernel<true><<<GEMM_BLOCKS + MASK_BLOCKS, 256, 0, stream>>>(
            attn, pos, E, W, bias, ws, out);
    } else {
        fused_kernel<false><<<GEMM_BLOCKS + MASK_BLOCKS, 256, 0, stream>>>(
            attn, pos, E, W, bias, nullptr, out);
    }
}

// Round 7
// 149.969 us; speedup vs baseline: 1.6144x; 1.0047x over previous
//
#include <hip/hip_runtime.h>
#include <hip/hip_bf16.h>
#include <stdint.h>
#include <type_traits>

#define BSAMP 8192
#define NCLS 400
#define DIM 768
#define LOGITS_SIZE (16384LL * 400LL)
#define GEMM_BLOCKS 1280    // 256 m-bands(64 rows) x 5 n(80 cols), n fastest
#define MASK_BLOCKS 4096    // 4 (sample,box) pairs per block, 1 per wave
#define W_ELEMS (NCLS * DIM)

typedef __attribute__((ext_vector_type(8))) short short8;
typedef __attribute__((ext_vector_type(4))) float floatx4;

// fp32 -> bf16 round-half-up, two at a time: 2 adds + 1 v_perm
__device__ inline unsigned int packbf(float a, float b) {
    unsigned int ua = __float_as_uint(a) + 0x8000u;
    unsigned int ub = __float_as_uint(b) + 0x8000u;
    return __builtin_amdgcn_perm(ub, ua, 0x07060302u);  // [ua.b2,ua.b3,ub.b2,ub.b3]
}

__device__ inline short8 cvt8(float4 lo, float4 hi) {
    union { unsigned int u[4]; short8 s; } r;
    r.u[0] = packbf(lo.x, lo.y);
    r.u[1] = packbf(lo.z, lo.w);
    r.u[2] = packbf(hi.x, hi.y);
    r.u[3] = packbf(hi.z, hi.w);
    return r.s;
}

// async global->LDS DMA, 16 B/lane, dest = wave-uniform base + lane*16.
// LDS side effect -> compiler cannot sink it across s_barrier (proven R6).
__device__ inline void gload16(const void* g, void* l) {
    __builtin_amdgcn_global_load_lds((const __attribute__((address_space(1))) void*)g,
                                     (__attribute__((address_space(3))) void*)l, 16, 0, 0);
}

// W fp32 -> bf16 pre-convert (0.6 MB into d_ws); re-run every launch (ws re-poisoned)
__global__ void cvtW_kernel(const float* __restrict__ W, unsigned short* __restrict__ ws) {
    int i = (blockIdx.x * 256 + threadIdx.x) * 4;
    if (i < W_ELEMS) {
        float4 f = *(const float4*)(W + i);
        uint2 r;
        r.x = packbf(f.x, f.y);
        r.y = packbf(f.z, f.w);
        *(uint2*)(ws + i) = r;
    }
}

// 2x2 tap: identical expressions to the reference's inner bilinear (coord chain hoisted)
__device__ inline float tap4(const float* m14, int r0, int c0, float fy, float fx) {
    int r1 = min(r0 + 1, 13);
    int c1 = min(c0 + 1, 13);
    float g00 = m14[r0 * 14 + c0];
    float g01 = m14[r0 * 14 + c1];
    float g10 = m14[r1 * 14 + c0];
    float g11 = m14[r1 * 14 + c1];
    return g00 * (1.f - fy) * (1.f - fx) + g01 * (1.f - fy) * fx +
           g10 * fy * (1.f - fx) + g11 * fy * fx;
}

struct MaskSm { float m14[4][208]; float a7[4][56]; float mv[4][56]; };  // 5120 B

template <bool USE_WS>
struct GemmSm {
    float A[2][64 * 32];                                                  // 16 KB fp32, swizzled
    typename std::conditional<USE_WS, unsigned short, float>::type B[2][80 * 32];
};  // 26624 B (ws) / 36864 B (fallback) -> 6 / 4 blocks per CU

template <bool USE_WS>
__global__ __launch_bounds__(256, 6) void fused_kernel(const float* __restrict__ attn,
                                                       const int* __restrict__ pos,
                                                       const float* __restrict__ E,
                                                       const float* __restrict__ W,
                                                       const float* __restrict__ bias,
                                                       const unsigned short* __restrict__ wsW,
                                                       float* __restrict__ out) {
    __shared__ __align__(16) union SmU {
        GemmSm<USE_WS> g;
        MaskSm m;
    } sm;

    const int bx = blockIdx.x;
    const int t  = threadIdx.x;
    const int wv = t >> 6, ln = t & 63;

    if (bx < GEMM_BLOCKS) {
        // ============ GEMM: 64(M) x 80(N), BK=32, async 2-deep LDS pipeline ============
        const int n0 = (bx % 5) * 80;     // n fastest: 5 sharers of an A-band adjacent
        const int m0 = (bx / 5) * 64;
        const int quad = ln >> 4, l16 = ln & 15;

        // A: [row][32 fp32]; phys chunk c (4 fp32) of row r holds logical chunk c^(r&7)
        auto stageA = [&](int k0, float* buf) {
#pragma unroll
            for (int j = 0; j < 2; ++j) {
                int r = wv * 16 + j * 8 + (ln >> 3);
                int c = ln & 7;
                const float* src = E + (size_t)(m0 + r) * DIM + k0 + 4 * (c ^ (r & 7));
                gload16(src, buf + (wv * 16 + j * 8) * 32);
            }
        };
        // B bf16: [n][32 bf16]; phys chunk c (8 bf16) of row n holds logical chunk c^((n>>1)&3)
        auto stageBw = [&](int k0, unsigned short* buf) {
            for (int j = wv; j < 5; j += 4) {
                int row = j * 16 + (ln >> 2);
                int c = ln & 3;
                const unsigned short* src = wsW + (size_t)(n0 + row) * DIM + k0 + 8 * (c ^ ((row >> 1) & 3));
                gload16(src, buf + (j * 16) * 32);
            }
        };
        // B fp32 fallback: same scheme as A
        auto stageBf = [&](int k0, float* buf) {
            for (int j = wv; j < 10; j += 4) {
                int r = j * 8 + (ln >> 3);
                int c = ln & 7;
                const float* src = W + (size_t)(n0 + r) * DIM + k0 + 4 * (c ^ (r & 7));
                gload16(src, buf + (j * 8) * 32);
            }
        };
        auto stage = [&](int k0, int buf) {
            stageA(k0, sm.g.A[buf]);
            if constexpr (USE_WS) stageBw(k0, sm.g.B[buf]);
            else stageBf(k0, (float*)sm.g.B[buf]);
        };

        floatx4 acc[5];
#pragma unroll
        for (int ni = 0; ni < 5; ++ni) acc[ni] = (floatx4){0.f, 0.f, 0.f, 0.f};

        stage(0, 0);
        stage(32, 1);
        __syncthreads();   // drain prologue

        for (int it = 0; it < 24; ++it) {
            const int cur = it & 1;

            // A frag: row = wv*16 + l16 (rx = l16&7 since wv*16 % 8 == 0)
            short8 af;
            {
                int rx = l16 & 7;
                const float* rp = sm.g.A[cur] + (wv * 16 + l16) * 32;
                float4 lo = *(const float4*)(rp + (((quad << 1) ^ rx) << 2));
                float4 hi = *(const float4*)(rp + ((((quad << 1) | 1) ^ rx) << 2));
                af = cvt8(lo, hi);
            }
#pragma unroll
            for (int ni = 0; ni < 5; ++ni) {
                int row = ni * 16 + l16;
                short8 bfr;
                if constexpr (USE_WS) {
                    bfr = *(const short8*)(sm.g.B[cur] + row * 32 + 8 * (quad ^ ((row >> 1) & 3)));
                } else {
                    int rx = row & 7;
                    const float* rp = (const float*)sm.g.B[cur] + row * 32;
                    float4 lo = *(const float4*)(rp + (((quad << 1) ^ rx) << 2));
                    float4 hi = *(const float4*)(rp + ((((quad << 1) | 1) ^ rx) << 2));
                    bfr = cvt8(lo, hi);
                }
                acc[ni] = __builtin_amdgcn_mfma_f32_16x16x32_bf16(af, bfr, acc[ni], 0, 0, 0);
            }

            __syncthreads();                          // readers of buf[cur] done; drains in-flight stage
            if (it < 22) stage((it + 2) * 32, cur);   // barrier-pinned issue, 1 compute-phase of cover
        }

        // epilogue: C/D layout col=lane&15, row=quad*4+reg (HW-verified)
        const int rowBase = m0 + wv * 16 + quad * 4;
#pragma unroll
        for (int ni = 0; ni < 5; ++ni) {
            int col = n0 + ni * 16 + l16;
            float bv = bias[col];
#pragma unroll
            for (int r = 0; r < 4; ++r) {
                out[(size_t)(rowBase + r) * NCLS + col] = acc[ni][r] + bv;
            }
        }
    } else {
        // ============ mask path: 4 (sample,box) pairs per block, 1 per wave ============
        const int p = (bx - GEMM_BLOCKS) * 4 + wv;   // 0..16383 output row
        const int b = p & (BSAMP - 1);
        const int o = p >> 13;
        float* m14 = sm.m.m14[wv];

        for (int i = ln; i < 196; i += 64) m14[i] = attn[(size_t)b * 196 + i];

        const int* pb = pos + (size_t)b * 12;
        const float topf  = (float)(pb[o * 4 + 0] - pb[8]);
        const float leftf = (float)(pb[o * 4 + 1] - pb[9]);
        const float oH = (float)pb[o * 4 + 2];
        const float oW = (float)pb[o * 4 + 3];
        const float eH = (float)pb[10];
        const float eW = (float)pb[11];
        __syncthreads();

        const int i7 = ln / 7, j7 = ln - i7 * 7;
        if (ln < 49) {
            // hoisted coordinate chains (identical expressions to reference; computed once)
            int   cI[2][2];  float cF[2][2];  float wxs[2];   // [dx][which X]
            int   rI[2][2];  float rF[2][2];  float wys[2];   // [dy][which Y]
#pragma unroll
            for (int dx = 0; dx < 2; ++dx) {
                int ox = 2 * j7 + dx;
                float tx = fmaxf((ox + 0.5f) * oW / 14.0f - 0.5f, 0.0f);
                float x0 = floorf(tx);
                float x1 = fminf(x0 + 1.0f, oW - 1.0f);
                wxs[dx] = tx - x0;
                float X0 = leftf + x0, X1 = leftf + x1;
                float sx0 = fmaxf((X0 + 0.5f) * 14.0f / eW - 0.5f, 0.0f);
                float c0f = floorf(sx0);
                cI[dx][0] = (int)c0f; cF[dx][0] = sx0 - c0f;
                float sx1 = fmaxf((X1 + 0.5f) * 14.0f / eW - 0.5f, 0.0f);
                float c1f = floorf(sx1);
                cI[dx][1] = (int)c1f; cF[dx][1] = sx1 - c1f;
            }
#pragma unroll
            for (int dy = 0; dy < 2; ++dy) {
                int oy = 2 * i7 + dy;
                float ty = fmaxf((oy + 0.5f) * oH / 14.0f - 0.5f, 0.0f);
                float y0 = floorf(ty);
                float y1 = fminf(y0 + 1.0f, oH - 1.0f);
                wys[dy] = ty - y0;
                float Y0 = topf + y0, Y1 = topf + y1;
                float sy0 = fmaxf((Y0 + 0.5f) * 14.0f / eH - 0.5f, 0.0f);
                float r0f = floorf(sy0);
                rI[dy][0] = (int)r0f; rF[dy][0] = sy0 - r0f;
                float sy1 = fmaxf((Y1 + 0.5f) * 14.0f / eH - 0.5f, 0.0f);
                float r1f = floorf(sy1);
                rI[dy][1] = (int)r1f; rF[dy][1] = sy1 - r1f;
            }

            float s = 0.f;
#pragma unroll
            for (int dy = 0; dy < 2; ++dy) {
                float wy = wys[dy];
#pragma unroll
                for (int dx = 0; dx < 2; ++dx) {
                    float wx = wxs[dx];
                    float v00 = tap4(m14, rI[dy][0], cI[dx][0], rF[dy][0], cF[dx][0]);
                    float v01 = tap4(m14, rI[dy][0], cI[dx][1], rF[dy][0], cF[dx][1]);
                    float v10 = tap4(m14, rI[dy][1], cI[dx][0], rF[dy][1], cF[dx][0]);
                    float v11 = tap4(m14, rI[dy][1], cI[dx][1], rF[dy][1], cF[dx][1]);
                    float cm = v00 * (1.f - wy) * (1.f - wx) + v01 * (1.f - wy) * wx +
                               v10 * wy * (1.f - wx) + v11 * wy * wx;
                    s += cm;
                }
            }
            sm.m.a7[wv][ln] = s * 0.25f;
        }
        __syncthreads();

        if (ln < 49) {  // stable top-25 rank (jax.lax.top_k tie-break to lower index)
            float mine = sm.m.a7[wv][ln];
            int cnt = 0;
#pragma unroll 7
            for (int s2 = 0; s2 < 49; ++s2) {
                float v = sm.m.a7[wv][s2];
                cnt += (v > mine) || (v == mine && s2 < ln);
            }
            sm.m.mv[wv][ln] = (cnt < 25) ? 0.0f : 1.0f;
        }
        __syncthreads();

        float* ob = out + LOGITS_SIZE + (size_t)p * 196;
        for (int i = ln; i < 196; i += 64) {
            int oy = i / 14, ox = i - oy * 14;
            ob[i] = sm.m.mv[wv][(oy >> 1) * 7 + (ox >> 1)];
        }
    }
}

extern "C" void kernel_launch(void* const* d_in, const int* in_sizes, int n_in,
                              void* d_out, int out_size, void* d_ws, size_t ws_size,
                              hipStream_t stream) {
    const float* attn = (const float*)d_in[0];
    const int*   pos  = (const int*)d_in[1];
    const float* E    = (const float*)d_in[2];
    const float* W    = (const float*)d_in[3];
    const float* bias = (const float*)d_in[4];
    float* out = (float*)d_out;

    if (ws_size >= (size_t)W_ELEMS * 2) {
        unsigned short* ws = (unsigned short*)d_ws;
        cvtW_kernel<<<300, 256, 0, stream>>>(W, ws);
        fused_kernel<true><<<GEMM_BLOCKS + MASK_BLOCKS, 256, 0, stream>>>(
            attn, pos, E, W, bias, ws, out);
    } else {
        fused_kernel<false><<<GEMM_BLOCKS + MASK_BLOCKS, 256, 0, stream>>>(
            attn, pos, E, W, bias, nullptr, out);
    }
}